// Round 6
// baseline (519.859 us; speedup 1.0000x reference)
//
#include <hip/hip_runtime.h>

#define NA 100000
#define NP 200000
#define NT 50000
#define E_AP 400000
#define E_PA 400000
#define E_TP 300000
#define E_TOT (E_AP + E_TP + E_PA)
#define HD 64
#define NOUT 4
#define NEG 0.01f
#define M_CNT (2 * NP + NA)          /* 500000 concatenated count slots */
#define SCAN_NB ((M_CNT + 1023) / 1024)

typedef __attribute__((ext_vector_type(8))) short bf16x8;
typedef __attribute__((ext_vector_type(4))) float f32x4;

static __device__ __forceinline__ short f2bf(float f) {
  unsigned u = __float_as_uint(f);
  unsigned r = (u + 0x7FFFu + ((u >> 16) & 1u)) >> 16;  // RNE
  return (short)r;
}
static __device__ __forceinline__ float bflo(unsigned u) {
  return __uint_as_float(u << 16);
}
static __device__ __forceinline__ float bfhi(unsigned u) {
  return __uint_as_float(u & 0xFFFF0000u);
}

// weighted bf16x8 accumulate; w==1.0 is exact add, w==0.0 is exact no-op.
static __device__ __forceinline__ void acc8(float* acc, uint4 u, float w) {
  acc[0] = fmaf(w, bflo(u.x), acc[0]);
  acc[1] = fmaf(w, bfhi(u.x), acc[1]);
  acc[2] = fmaf(w, bflo(u.y), acc[2]);
  acc[3] = fmaf(w, bfhi(u.y), acc[3]);
  acc[4] = fmaf(w, bflo(u.z), acc[4]);
  acc[5] = fmaf(w, bfhi(u.z), acc[5]);
  acc[6] = fmaf(w, bflo(u.w), acc[6]);
  acc[7] = fmaf(w, bfhi(u.w), acc[7]);
}

// ---------------- weight prep (parallel) + cnt zeroing fused ----------------
#define R_NP 16384
#define R_NA 32768
#define R_TP 36864
#define R_BLC 36928
#define R_WFL 37184
#define R_WFR 37440
#define R_BF 37444
#define BZ_NB ((M_CNT / 4 + 255) / 256)   /* 489 blocks covers zeroing + build */
__global__ __launch_bounds__(256) void build_zero_kernel(
    const float* __restrict__ l1_ap_Wl, const float* __restrict__ l1_ap_bl,
    const float* __restrict__ l1_ap_Wr,
    const float* __restrict__ l1_pa_Wl, const float* __restrict__ l1_pa_bl,
    const float* __restrict__ l1_pa_Wr,
    const float* __restrict__ l1_tp_Wl, const float* __restrict__ l1_tp_bl,
    const float* __restrict__ l1_tp_Wr,
    const float* __restrict__ l2_Wl, const float* __restrict__ l2_bl,
    const float* __restrict__ l2_Wr,
    const float* __restrict__ lin_W, const float* __restrict__ lin_b,
    short* __restrict__ Wt_np, short* __restrict__ Wt_na, short* __restrict__ Wt_tp,
    float* __restrict__ blc, float* __restrict__ Wfl, float* __restrict__ Wfr,
    float* __restrict__ bf, int* __restrict__ cnt) {
  int t = blockIdx.x * 256 + threadIdx.x;
  // zero the degree counters (replaces hipMemsetAsync)
  int z4 = t * 4;
  if (z4 < M_CNT) *(int4*)(cnt + z4) = make_int4(0, 0, 0, 0);

  if (t < R_NP) {
    int c = t >> 7, k = t & 127;
    float v = (c < 64) ? l1_pa_Wl[k * 64 + c]
                       : (l1_ap_Wr[k * 64 + (c - 64)] + l1_tp_Wr[k * 64 + (c - 64)]);
    Wt_np[t] = f2bf(v);
  } else if (t < R_NA) {
    int i = t - R_NP;
    int c = i >> 7, k = i & 127;
    float v = (c < 64) ? l1_ap_Wl[k * 64 + c] : l1_pa_Wr[k * 64 + (c - 64)];
    Wt_na[i] = f2bf(v);
  } else if (t < R_TP) {
    int i = t - R_NA;
    int c = i >> 6, k = i & 63;
    Wt_tp[i] = f2bf(l1_tp_Wl[k * 64 + c]);
  } else if (t < R_BLC) {
    int c = t - R_TP;
    blc[c] = l1_ap_bl[c] + l1_tp_bl[c];
  } else if (t < R_WFL) {
    int i = t - R_BLC;
    int k = i >> 2, c = i & 3;
    float s = 0.f;
    for (int j = 0; j < HD; ++j) s += l2_Wl[k * HD + j] * lin_W[j * NOUT + c];
    Wfl[i] = s;
  } else if (t < R_WFR) {
    int i = t - R_WFL;
    int k = i >> 2, c = i & 3;
    float s = 0.f;
    for (int j = 0; j < HD; ++j) s += l2_Wr[k * HD + j] * lin_W[j * NOUT + c];
    Wfr[i] = s;
  } else if (t < R_BF) {
    int c = t - R_WFR;
    float s = lin_b[c];
    for (int j = 0; j < HD; ++j) s += l2_bl[j] * lin_W[j * NOUT + c];
    bf[c] = s;
  }
}

// ---------------- degree counting, int4-vectorized ----------------
__global__ __launch_bounds__(256) void count_all(const int* __restrict__ dst_ap,
                                                 const int* __restrict__ dst_tp,
                                                 const int* __restrict__ dst_pa,
                                                 int* __restrict__ cnt) {
  int i4 = (blockIdx.x * 256 + threadIdx.x) * 4;
  const int* p;
  int base;
  if (i4 < E_AP) { p = dst_ap + i4; base = 0; }
  else if (i4 < E_AP + E_TP) { p = dst_tp + (i4 - E_AP); base = NP; }
  else if (i4 < E_TOT) { p = dst_pa + (i4 - E_AP - E_TP); base = 2 * NP; }
  else return;
  int4 d = *(const int4*)p;
  atomicAdd(&cnt[base + d.x], 1);
  atomicAdd(&cnt[base + d.y], 1);
  atomicAdd(&cnt[base + d.z], 1);
  atomicAdd(&cnt[base + d.w], 1);
}

// ---------------- exclusive scan (3 kernels) ----------------
__global__ __launch_bounds__(256) void scan1(const int* __restrict__ cnt,
                                             int* __restrict__ offs,
                                             int* __restrict__ bsum) {
  __shared__ int ts[256];
  int t = threadIdx.x;
  int idx = blockIdx.x * 1024 + t * 4;
  int4 v = make_int4(0, 0, 0, 0);
  if (idx < M_CNT) v = *(const int4*)(cnt + idx);
  int s = v.x + v.y + v.z + v.w;
  ts[t] = s;
  __syncthreads();
  for (int off = 1; off < 256; off <<= 1) {
    int a = (t >= off) ? ts[t - off] : 0;
    __syncthreads();
    ts[t] += a;
    __syncthreads();
  }
  int excl = ts[t] - s;
  if (idx < M_CNT) {
    int4 o;
    o.x = excl; o.y = o.x + v.x; o.z = o.y + v.y; o.w = o.z + v.z;
    *(int4*)(offs + idx) = o;
  }
  if (t == 255) bsum[blockIdx.x] = ts[255];
}

__global__ __launch_bounds__(256) void scan2(int* __restrict__ bsum, int nb) {
  __shared__ int ts[256];
  __shared__ int carrysh;
  int t = threadIdx.x;
  int carry = 0;
  for (int base = 0; base < nb; base += 256) {
    int v = (base + t < nb) ? bsum[base + t] : 0;
    ts[t] = v;
    __syncthreads();
    for (int off = 1; off < 256; off <<= 1) {
      int a = (t >= off) ? ts[t - off] : 0;
      __syncthreads();
      ts[t] += a;
      __syncthreads();
    }
    if (base + t < nb) bsum[base + t] = carry + ts[t] - v;
    if (t == 255) carrysh = ts[255];
    __syncthreads();
    carry += carrysh;
    __syncthreads();
  }
}

__global__ __launch_bounds__(256) void scan3(int* __restrict__ offs,
                                             const int* __restrict__ bsum) {
  int add = bsum[blockIdx.x];
  int idx = blockIdx.x * 1024 + threadIdx.x * 4;
  if (idx < M_CNT) {
    int4 v = *(const int4*)(offs + idx);
    v.x += add; v.y += add; v.z += add; v.w += add;
    *(int4*)(offs + idx) = v;
  }
}

// ---------------- bucket edges by dst, int4-vectorized loads ----------------
__global__ __launch_bounds__(256) void bucket_kernel(
    const int* __restrict__ src_ap, const int* __restrict__ dst_ap,
    const int* __restrict__ src_tp, const int* __restrict__ dst_tp,
    const int* __restrict__ src_pa, const int* __restrict__ dst_pa,
    int* __restrict__ offs, int* __restrict__ ebuf) {
  int i4 = (blockIdx.x * 256 + threadIdx.x) * 4;
  const int *sp, *dp;
  int base;
  if (i4 < E_AP) { sp = src_ap + i4; dp = dst_ap + i4; base = 0; }
  else if (i4 < E_AP + E_TP) { int j = i4 - E_AP; sp = src_tp + j; dp = dst_tp + j; base = NP; }
  else if (i4 < E_TOT) { int j = i4 - E_AP - E_TP; sp = src_pa + j; dp = dst_pa + j; base = 2 * NP; }
  else return;
  int4 s = *(const int4*)sp;
  int4 d = *(const int4*)dp;
  ebuf[atomicAdd(&offs[base + d.x], 1)] = s.x;
  ebuf[atomicAdd(&offs[base + d.y], 1)] = s.y;
  ebuf[atomicAdd(&offs[base + d.z], 1)] = s.z;
  ebuf[atomicAdd(&offs[base + d.w], 1)] = s.w;
}

// ---------------- MFMA bf16 GEMM v4: persistent blocks, software pipeline ----
// Each block keeps ONE weight matrix resident in LDS (swizzled, as verified in
// v3) and loops grid-stride over 64-row tiles of its partition. Per iteration:
// issue next tile's A-loads into the alternate register buffer, then
// convert+MFMA the current one -- ~6us of compute/writeback covers the HBM
// latency of the prefetch. Out staging is wave-local (4KB/wave, no barrier).
template <int K, int COLS, bool HAS_OUT1>
static __device__ __forceinline__ void gemm_persist(
    const float* __restrict__ X, const short* __restrict__ Wt,
    const float* __restrict__ bias1,
    unsigned short* __restrict__ out0, unsigned short* __restrict__ out1,
    int N, int nt, int bidp, int nb, unsigned short* __restrict__ lds) {
  constexpr int NSTEP = K / 32;
  constexpr int NTILE = COLS / 16;
  constexpr int WROWB = K * 2;          // weight row bytes (256 / 128)
  constexpr int WBYTES = COLS * K * 2;  // 32KB / 8KB
  constexpr int OROWB = COLS * 2;       // out-stage row bytes
  constexpr int OWB = 16 * COLS * 2;    // per-wave out-stage bytes (4KB / 2KB)
  const int t = threadIdx.x;
  const int lane = t & 63;
  const int w = t >> 6;
  const int m = lane & 15;
  const int quad = lane >> 4;

  unsigned short* outw = lds + WBYTES / 2 + w * (OWB / 2);

  float4 rawA[2 * NSTEP], rawB[2 * NSTEP];
  float badd[HAS_OUT1 ? NTILE / 2 : 1];

  auto LOADRAW = [&](float4* buf, int tile) {
    const int row = tile * 64 + w * 16 + m;
    const float* xr = X + (size_t)min(row, N - 1) * K + quad * 8;
#pragma unroll
    for (int s = 0; s < NSTEP; ++s) {
      buf[2 * s] = *(const float4*)(xr + s * 32);
      buf[2 * s + 1] = *(const float4*)(xr + s * 32 + 4);
    }
  };

  auto COMPUTE = [&](float4* buf, int tile) {
    bf16x8 af[NSTEP];
#pragma unroll
    for (int s = 0; s < NSTEP; ++s) {
      float4 v0 = buf[2 * s], v1 = buf[2 * s + 1];
      bf16x8 a;
      a[0] = f2bf(v0.x); a[1] = f2bf(v0.y); a[2] = f2bf(v0.z); a[3] = f2bf(v0.w);
      a[4] = f2bf(v1.x); a[5] = f2bf(v1.y); a[6] = f2bf(v1.z); a[7] = f2bf(v1.w);
      af[s] = a;
    }
    f32x4 acc[NTILE];
#pragma unroll
    for (int ct = 0; ct < NTILE; ++ct) acc[ct] = (f32x4){0.f, 0.f, 0.f, 0.f};
#pragma unroll
    for (int ct = 0; ct < NTILE; ++ct) {
      const int wrow = ct * 16 + m;
      const int swx = (wrow & 7) << 4;
#pragma unroll
      for (int s = 0; s < NSTEP; ++s) {
        const int byte = wrow * WROWB + s * 64 + quad * 16;
        const bf16x8 b = *(const bf16x8*)((const char*)lds + (byte ^ swx));
        acc[ct] = __builtin_amdgcn_mfma_f32_16x16x32_bf16(af[s], b, acc[ct], 0, 0, 0);
      }
    }
    // stage wave-local 16xCOLS tile (swizzled), then coalesced 16B writeback
#pragma unroll
    for (int ct = 0; ct < NTILE; ++ct) {
      const int col = ct * 16 + m;
      float add = 0.f;
      if constexpr (HAS_OUT1) {
        if (ct >= NTILE / 2) add = badd[ct - NTILE / 2];
      }
#pragma unroll
      for (int rg = 0; rg < 4; ++rg) {
        const int r = quad * 4 + rg;
        const int bo = r * OROWB + col * 2;
        *(unsigned short*)((char*)outw + (bo ^ ((r & 7) << 4))) =
            (unsigned short)f2bf(acc[ct][rg] + add);
      }
    }
#pragma unroll
    for (int i2 = 0; i2 < OWB / 1024; ++i2) {
      const int byte = lane * 16 + i2 * 1024;
      const int r = byte / OROWB;
      const int colb = byte - r * OROWB;
      const uint4 v = *(const uint4*)((const char*)outw + (byte ^ ((r & 7) << 4)));
      const int grow = tile * 64 + w * 16 + r;
      if (grow < N) {
        unsigned short* dst = (HAS_OUT1 && colb >= 128) ? out1 : out0;
        const int off = HAS_OUT1 ? (colb & 127) : colb;
        *(uint4*)((char*)dst + (size_t)grow * (HD * 2) + off) = v;
      }
    }
  };

  // prologue A-load first so HBM latency overlaps the W staging
  LOADRAW(rawA, bidp);

  {  // stage W once, swizzled (verified v3 scheme)
    const char* wsrc = (const char*)Wt;
    char* wdst = (char*)lds;
#pragma unroll
    for (int i = 0; i < WBYTES / 4096; ++i) {
      const int byte = t * 16 + i * 4096;
      const uint4 v = *(const uint4*)(wsrc + byte);
      const int row = byte / WROWB;
      *(uint4*)(wdst + (byte ^ ((row & 7) << 4))) = v;
    }
  }
  __syncthreads();

  if constexpr (HAS_OUT1) {
#pragma unroll
    for (int j = 0; j < NTILE / 2; ++j) badd[j] = bias1[j * 16 + m];
  }

  // 2-step pipeline, explicit buffers (no runtime-indexed arrays -> no scratch)
  const int nit = (nt - 1 - bidp) / nb + 1;
  int tile = bidp;
  int i = 0;
  for (;;) {
    int tnext = tile + nb;
    bool more = (i + 1 < nit);
    if (more) LOADRAW(rawB, tnext);
    COMPUTE(rawA, tile);
    ++i;
    if (!more) break;
    tile = tnext;
    tnext = tile + nb;
    more = (i + 1 < nit);
    if (more) LOADRAW(rawA, tnext);
    COMPUTE(rawB, tile);
    ++i;
    if (!more) break;
    tile = tnext;
  }
}

// persistent grid: 3 blocks/CU, statically partitioned across the 3 GEMMs
// proportional to their tile counts (each block stages its W exactly once).
#define PERS_NBLK 768
#define PB_P 439
#define PB_A 219
#define PB_T (PERS_NBLK - PB_P - PB_A)
#define PT_P ((NP + 63) / 64)   /* 3125 tiles */
#define PT_A ((NA + 63) / 64)   /* 1563 tiles */
#define PT_T ((NT + 63) / 64)   /* 782 tiles  */

__global__ __launch_bounds__(256, 3) void gemm_all(
    const float* __restrict__ x_paper, const float* __restrict__ x_author,
    const float* __restrict__ x_term,
    const short* __restrict__ Wt_np, const short* __restrict__ Wt_na,
    const short* __restrict__ Wt_tp,
    const float* __restrict__ blc, const float* __restrict__ l1_pa_bl,
    unsigned short* __restrict__ yp, unsigned short* __restrict__ P1root,
    unsigned short* __restrict__ ya, unsigned short* __restrict__ A1root,
    unsigned short* __restrict__ yt) {
  __shared__ unsigned short lds[24576];  // 32KB W + 4 waves x 4KB out stage
  int b = blockIdx.x;
  if (b < PB_P) {
    gemm_persist<128, 128, true>(x_paper, Wt_np, blc, yp, P1root, NP, PT_P, b, PB_P, lds);
  } else if (b < PB_P + PB_A) {
    gemm_persist<128, 128, true>(x_author, Wt_na, l1_pa_bl, ya, A1root, NA, PT_A,
                                 b - PB_P, PB_A, lds);
  } else {
    gemm_persist<64, 64, false>(x_term, Wt_tp, nullptr, yt, nullptr, NT, PT_T,
                                b - PB_P - PB_A, PB_T, lds);
  }
}

// ---------------- paper aggregation: 8 lanes/paper, 2-way edge unroll ------
// lane = 8g + l; group g handles paper p; lane owns cols 8l..8l+7 (uint4 = 8 bf16).
// 2-way unroll + predication keeps 4 independent row-gathers in flight.
__global__ __launch_bounds__(256) void paper_agg(
    const unsigned short* __restrict__ ya, const unsigned short* __restrict__ yt,
    const unsigned short* __restrict__ P1root,
    const int* __restrict__ cnt, const int* __restrict__ offs,
    const int* __restrict__ ebuf, const float* __restrict__ Wfl,
    float* __restrict__ z) {
  const int wv = threadIdx.x >> 6;
  const int lane = threadIdx.x & 63;
  const int g = lane >> 3;
  const int l = lane & 7;
  const int p = blockIdx.x * 32 + wv * 8 + g;
  const bool pv = p < NP;
  const int pc = pv ? p : NP - 1;

  const int cA = cnt[pc], cT = cnt[NP + pc];
  const int startA = offs[pc] - cA;
  const int startT = offs[NP + pc] - cT;

  const unsigned short* yab = ya + 8 * l;
  const unsigned short* ytb = yt + 8 * l;

  float accA[8], accT[8];
#pragma unroll
  for (int j = 0; j < 8; ++j) { accA[j] = 0.f; accT[j] = 0.f; }

  const int mx = max(cA, cT);
  for (int i = 0; i < mx; i += 2) {
    const bool a0 = i < cA, a1 = i + 1 < cA;
    const bool t0 = i < cT, t1 = i + 1 < cT;
    // index reads may overshoot a segment but stay inside ebuf (regions are
    // contiguous; max overshoot < max degree). Inactive slots clamp to row 0.
    int sA0 = ebuf[startA + i];
    int sA1 = ebuf[startA + i + 1];
    int sT0 = ebuf[startT + i];
    int sT1 = ebuf[startT + i + 1];
    sA0 = a0 ? sA0 : 0;
    sA1 = a1 ? sA1 : 0;
    sT0 = t0 ? sT0 : 0;
    sT1 = t1 ? sT1 : 0;
    const uint4 uA0 = *(const uint4*)(yab + (size_t)sA0 * HD);
    const uint4 uA1 = *(const uint4*)(yab + (size_t)sA1 * HD);
    const uint4 uT0 = *(const uint4*)(ytb + (size_t)sT0 * HD);
    const uint4 uT1 = *(const uint4*)(ytb + (size_t)sT1 * HD);
    acc8(accA, uA0, a0 ? 1.f : 0.f);
    acc8(accA, uA1, a1 ? 1.f : 0.f);
    acc8(accT, uT0, t0 ? 1.f : 0.f);
    acc8(accT, uT1, t1 ? 1.f : 0.f);
  }

  const float rA = 1.0f / (float)max(cA, 1);
  const float rT = 1.0f / (float)max(cT, 1);
  uint4 rt = *(const uint4*)(P1root + (size_t)pc * HD + 8 * l);
  float v[8];
  v[0] = bflo(rt.x); v[1] = bfhi(rt.x); v[2] = bflo(rt.y); v[3] = bfhi(rt.y);
  v[4] = bflo(rt.z); v[5] = bfhi(rt.z); v[6] = bflo(rt.w); v[7] = bfhi(rt.w);
  float4 pz = make_float4(0.f, 0.f, 0.f, 0.f);
#pragma unroll
  for (int j = 0; j < 8; ++j) {
    float x = v[j] + accA[j] * rA + accT[j] * rT;
    x = fmaxf(x, NEG * x);  // lrelu
    float4 wf = *(const float4*)(Wfl + (8 * l + j) * 4);
    pz.x += x * wf.x; pz.y += x * wf.y; pz.z += x * wf.z; pz.w += x * wf.w;
  }
#pragma unroll
  for (int m = 1; m < 8; m <<= 1) {
    pz.x += __shfl_xor(pz.x, m);
    pz.y += __shfl_xor(pz.y, m);
    pz.z += __shfl_xor(pz.z, m);
    pz.w += __shfl_xor(pz.w, m);
  }
  if (l == 0 && pv) *(float4*)(z + (size_t)p * NOUT) = pz;
}

// ---------------- author aggregation: 8 lanes/author, 2-way edge unroll ----
__global__ __launch_bounds__(256) void author_agg(
    const unsigned short* __restrict__ yp, const unsigned short* __restrict__ A1root,
    const float* __restrict__ z,
    const int* __restrict__ cnt, const int* __restrict__ offs,
    const int* __restrict__ ebuf, const float* __restrict__ Wfr,
    const float* __restrict__ bf, float* __restrict__ out) {
  const int wv = threadIdx.x >> 6;
  const int lane = threadIdx.x & 63;
  const int g = lane >> 3;
  const int l = lane & 7;
  const int a = blockIdx.x * 32 + wv * 8 + g;
  const bool av = a < NA;
  const int ac = av ? a : NA - 1;

  const int c = cnt[2 * NP + ac];
  const int start = offs[2 * NP + ac] - c;

  const unsigned short* ypb = yp + 8 * l;

  float acc[8];
#pragma unroll
  for (int j = 0; j < 8; ++j) acc[j] = 0.f;
  float4 az = make_float4(0.f, 0.f, 0.f, 0.f);

  for (int i = 0; i < c; i += 2) {
    const bool b1 = i + 1 < c;
    int s0 = ebuf[start + i];
    int s1 = ebuf[min(start + i + 1, E_TOT - 1)];  // pa region is last: clamp
    s1 = b1 ? s1 : 0;
    const uint4 u0 = *(const uint4*)(ypb + (size_t)s0 * HD);
    const uint4 u1 = *(const uint4*)(ypb + (size_t)s1 * HD);
    const float4 z0 = *(const float4*)(z + (size_t)s0 * NOUT);
    const float4 z1 = *(const float4*)(z + (size_t)s1 * NOUT);
    const float w1 = b1 ? 1.f : 0.f;
    acc8(acc, u0, 1.f);
    acc8(acc, u1, w1);
    az.x = fmaf(w1, z1.x, az.x + z0.x);
    az.y = fmaf(w1, z1.y, az.y + z0.y);
    az.z = fmaf(w1, z1.z, az.z + z0.z);
    az.w = fmaf(w1, z1.w, az.w + z0.w);
  }

  const float r = 1.0f / (float)max(c, 1);
  uint4 rt = *(const uint4*)(A1root + (size_t)ac * HD + 8 * l);
  float v[8];
  v[0] = bflo(rt.x); v[1] = bfhi(rt.x); v[2] = bflo(rt.y); v[3] = bfhi(rt.y);
  v[4] = bflo(rt.z); v[5] = bfhi(rt.z); v[6] = bflo(rt.w); v[7] = bfhi(rt.w);
  float4 o = make_float4(0.f, 0.f, 0.f, 0.f);
#pragma unroll
  for (int j = 0; j < 8; ++j) {
    float x = v[j] + acc[j] * r;
    x = fmaxf(x, NEG * x);
    float4 wf = *(const float4*)(Wfr + (8 * l + j) * 4);
    o.x += x * wf.x; o.y += x * wf.y; o.z += x * wf.z; o.w += x * wf.w;
  }
#pragma unroll
  for (int m = 1; m < 8; m <<= 1) {
    o.x += __shfl_xor(o.x, m);
    o.y += __shfl_xor(o.y, m);
    o.z += __shfl_xor(o.z, m);
    o.w += __shfl_xor(o.w, m);
  }
  if (l == 0 && av) {
    float4 b = *(const float4*)bf;
    o.x += az.x * r + b.x;
    o.y += az.y * r + b.y;
    o.z += az.z * r + b.z;
    o.w += az.w * r + b.w;
    *(float4*)(out + (size_t)a * NOUT) = o;
  }
}

extern "C" void kernel_launch(void* const* d_in, const int* in_sizes, int n_in,
                              void* d_out, int out_size, void* d_ws, size_t ws_size,
                              hipStream_t stream) {
  const float* x_author = (const float*)d_in[0];
  const float* x_paper  = (const float*)d_in[1];
  const float* x_term   = (const float*)d_in[2];
  const int* src_ap = (const int*)d_in[3];
  const int* dst_ap = (const int*)d_in[4];
  const int* src_pa = (const int*)d_in[5];
  const int* dst_pa = (const int*)d_in[6];
  const int* src_tp = (const int*)d_in[7];
  const int* dst_tp = (const int*)d_in[8];
  const float* l1_ap_Wl = (const float*)d_in[11];
  const float* l1_ap_bl = (const float*)d_in[12];
  const float* l1_ap_Wr = (const float*)d_in[13];
  const float* l1_pa_Wl = (const float*)d_in[17];
  const float* l1_pa_bl = (const float*)d_in[18];
  const float* l1_pa_Wr = (const float*)d_in[19];
  const float* l2_pa_Wl = (const float*)d_in[20];
  const float* l2_pa_bl = (const float*)d_in[21];
  const float* l2_pa_Wr = (const float*)d_in[22];
  const float* l1_tp_Wl = (const float*)d_in[23];
  const float* l1_tp_bl = (const float*)d_in[24];
  const float* l1_tp_Wr = (const float*)d_in[25];
  const float* lin_W = (const float*)d_in[35];
  const float* lin_b = (const float*)d_in[36];
  float* out = (float*)d_out;

  // workspace carve-up (byte-based, 16B aligned blocks)
  char* wsb = (char*)d_ws;
  auto carve = [&](size_t bytes) {
    char* p = wsb;
    wsb += (bytes + 15) & ~(size_t)15;
    return p;
  };
  unsigned short* ya = (unsigned short*)carve((size_t)NA * HD * 2);
  unsigned short* yp = (unsigned short*)carve((size_t)NP * HD * 2);
  unsigned short* yt = (unsigned short*)carve((size_t)NT * HD * 2);
  unsigned short* P1root = (unsigned short*)carve((size_t)NP * HD * 2);
  unsigned short* A1root = (unsigned short*)carve((size_t)NA * HD * 2);
  float* z = (float*)carve((size_t)NP * NOUT * 4);
  int* cnt = (int*)carve((size_t)M_CNT * 4);
  int* offs = (int*)carve((size_t)M_CNT * 4);
  int* bsum = (int*)carve((size_t)SCAN_NB * 4);
  int* ebuf = (int*)carve((size_t)E_TOT * 4);
  short* Wt_np = (short*)carve(128 * 128 * 2);
  short* Wt_na = (short*)carve(128 * 128 * 2);
  short* Wt_tp = (short*)carve(64 * 64 * 2);
  float* blc = (float*)carve(HD * 4);
  float* Wfl = (float*)carve(HD * NOUT * 4);
  float* Wfr = (float*)carve(HD * NOUT * 4);
  float* bf  = (float*)carve(NOUT * 4);

  // weight prep + cnt zeroing in one launch (memset folded in)
  build_zero_kernel<<<BZ_NB, 256, 0, stream>>>(
      l1_ap_Wl, l1_ap_bl, l1_ap_Wr, l1_pa_Wl, l1_pa_bl, l1_pa_Wr,
      l1_tp_Wl, l1_tp_bl, l1_tp_Wr, l2_pa_Wl, l2_pa_bl, l2_pa_Wr,
      lin_W, lin_b, Wt_np, Wt_na, Wt_tp, blc, Wfl, Wfr, bf, cnt);
  count_all<<<(E_TOT / 4 + 255) / 256, 256, 0, stream>>>(dst_ap, dst_tp, dst_pa, cnt);

  // exclusive scan of cnt -> offs
  scan1<<<SCAN_NB, 256, 0, stream>>>(cnt, offs, bsum);
  scan2<<<1, 256, 0, stream>>>(bsum, SCAN_NB);
  scan3<<<SCAN_NB, 256, 0, stream>>>(offs, bsum);

  // all three layer-1 GEMMs, persistent pipelined blocks
  gemm_all<<<PERS_NBLK, 256, 0, stream>>>(
      x_paper, x_author, x_term, Wt_np, Wt_na, Wt_tp, blc, l1_pa_bl,
      yp, P1root, ya, A1root, yt);

  // CSR bucket (offs becomes end-cursor; consumers use offs[g]-cnt[g] as start)
  bucket_kernel<<<(E_TOT / 4 + 255) / 256, 256, 0, stream>>>(src_ap, dst_ap, src_tp, dst_tp,
                                                             src_pa, dst_pa, offs, ebuf);

  // gather-based aggregation: 8 lanes/node, 8 nodes/wave, 2-way edge unroll
  paper_agg<<<(NP + 31) / 32, 256, 0, stream>>>(ya, yt, P1root, cnt, offs, ebuf, Wfl, z);
  author_agg<<<(NA + 31) / 32, 256, 0, stream>>>(yp, A1root, z, cnt, offs, ebuf, Wfr, bf, out);
}

// Round 7
// 469.418 us; speedup vs baseline: 1.1075x; 1.1075x over previous
//
#include <hip/hip_runtime.h>

#define NA 100000
#define NP 200000
#define NT 50000
#define E_AP 400000
#define E_PA 400000
#define E_TP 300000
#define E_TOT (E_AP + E_TP + E_PA)
#define HD 64
#define NOUT 4
#define NEG 0.01f
#define M_CNT (2 * NP + NA)          /* 500000 concatenated count slots */
#define SCAN_NB ((M_CNT + 1023) / 1024)

typedef __attribute__((ext_vector_type(8))) short bf16x8;
typedef __attribute__((ext_vector_type(4))) float f32x4;

static __device__ __forceinline__ short f2bf(float f) {
  unsigned u = __float_as_uint(f);
  unsigned r = (u + 0x7FFFu + ((u >> 16) & 1u)) >> 16;  // RNE
  return (short)r;
}
static __device__ __forceinline__ float bflo(unsigned u) {
  return __uint_as_float(u << 16);
}
static __device__ __forceinline__ float bfhi(unsigned u) {
  return __uint_as_float(u & 0xFFFF0000u);
}

// weighted bf16x8 accumulate; w==1.0 is exact add, w==0.0 is exact no-op.
static __device__ __forceinline__ void acc8(float* acc, uint4 u, float w) {
  acc[0] = fmaf(w, bflo(u.x), acc[0]);
  acc[1] = fmaf(w, bfhi(u.x), acc[1]);
  acc[2] = fmaf(w, bflo(u.y), acc[2]);
  acc[3] = fmaf(w, bfhi(u.y), acc[3]);
  acc[4] = fmaf(w, bflo(u.z), acc[4]);
  acc[5] = fmaf(w, bfhi(u.z), acc[5]);
  acc[6] = fmaf(w, bflo(u.w), acc[6]);
  acc[7] = fmaf(w, bfhi(u.w), acc[7]);
}

// ---------------- weight prep (parallel) + cnt zeroing fused ----------------
#define R_NP 16384
#define R_NA 32768
#define R_TP 36864
#define R_BLC 36928
#define R_WFL 37184
#define R_WFR 37440
#define R_BF 37444
#define BZ_NB ((M_CNT / 4 + 255) / 256)   /* 489 blocks covers zeroing + build */
__global__ __launch_bounds__(256) void build_zero_kernel(
    const float* __restrict__ l1_ap_Wl, const float* __restrict__ l1_ap_bl,
    const float* __restrict__ l1_ap_Wr,
    const float* __restrict__ l1_pa_Wl, const float* __restrict__ l1_pa_bl,
    const float* __restrict__ l1_pa_Wr,
    const float* __restrict__ l1_tp_Wl, const float* __restrict__ l1_tp_bl,
    const float* __restrict__ l1_tp_Wr,
    const float* __restrict__ l2_Wl, const float* __restrict__ l2_bl,
    const float* __restrict__ l2_Wr,
    const float* __restrict__ lin_W, const float* __restrict__ lin_b,
    short* __restrict__ Wt_np, short* __restrict__ Wt_na, short* __restrict__ Wt_tp,
    float* __restrict__ blc, float* __restrict__ Wfl, float* __restrict__ Wfr,
    float* __restrict__ bf, int* __restrict__ cnt) {
  int t = blockIdx.x * 256 + threadIdx.x;
  // zero the degree counters (replaces hipMemsetAsync)
  int z4 = t * 4;
  if (z4 < M_CNT) *(int4*)(cnt + z4) = make_int4(0, 0, 0, 0);

  if (t < R_NP) {
    int c = t >> 7, k = t & 127;
    float v = (c < 64) ? l1_pa_Wl[k * 64 + c]
                       : (l1_ap_Wr[k * 64 + (c - 64)] + l1_tp_Wr[k * 64 + (c - 64)]);
    Wt_np[t] = f2bf(v);
  } else if (t < R_NA) {
    int i = t - R_NP;
    int c = i >> 7, k = i & 127;
    float v = (c < 64) ? l1_ap_Wl[k * 64 + c] : l1_pa_Wr[k * 64 + (c - 64)];
    Wt_na[i] = f2bf(v);
  } else if (t < R_TP) {
    int i = t - R_NA;
    int c = i >> 6, k = i & 63;
    Wt_tp[i] = f2bf(l1_tp_Wl[k * 64 + c]);
  } else if (t < R_BLC) {
    int c = t - R_TP;
    blc[c] = l1_ap_bl[c] + l1_tp_bl[c];
  } else if (t < R_WFL) {
    int i = t - R_BLC;
    int k = i >> 2, c = i & 3;
    float s = 0.f;
    for (int j = 0; j < HD; ++j) s += l2_Wl[k * HD + j] * lin_W[j * NOUT + c];
    Wfl[i] = s;
  } else if (t < R_WFR) {
    int i = t - R_WFL;
    int k = i >> 2, c = i & 3;
    float s = 0.f;
    for (int j = 0; j < HD; ++j) s += l2_Wr[k * HD + j] * lin_W[j * NOUT + c];
    Wfr[i] = s;
  } else if (t < R_BF) {
    int c = t - R_WFR;
    float s = lin_b[c];
    for (int j = 0; j < HD; ++j) s += l2_bl[j] * lin_W[j * NOUT + c];
    bf[c] = s;
  }
}

// ---------------- degree counting, int4-vectorized ----------------
__global__ __launch_bounds__(256) void count_all(const int* __restrict__ dst_ap,
                                                 const int* __restrict__ dst_tp,
                                                 const int* __restrict__ dst_pa,
                                                 int* __restrict__ cnt) {
  int i4 = (blockIdx.x * 256 + threadIdx.x) * 4;
  const int* p;
  int base;
  if (i4 < E_AP) { p = dst_ap + i4; base = 0; }
  else if (i4 < E_AP + E_TP) { p = dst_tp + (i4 - E_AP); base = NP; }
  else if (i4 < E_TOT) { p = dst_pa + (i4 - E_AP - E_TP); base = 2 * NP; }
  else return;
  int4 d = *(const int4*)p;
  atomicAdd(&cnt[base + d.x], 1);
  atomicAdd(&cnt[base + d.y], 1);
  atomicAdd(&cnt[base + d.z], 1);
  atomicAdd(&cnt[base + d.w], 1);
}

// ---------------- exclusive scan (2 kernels; block-offset add folded into
// bucket/agg consumers via bsum lookup) ----------------
__global__ __launch_bounds__(256) void scan1(const int* __restrict__ cnt,
                                             int* __restrict__ offs,
                                             int* __restrict__ bsum) {
  __shared__ int ts[256];
  int t = threadIdx.x;
  int idx = blockIdx.x * 1024 + t * 4;
  int4 v = make_int4(0, 0, 0, 0);
  if (idx < M_CNT) v = *(const int4*)(cnt + idx);
  int s = v.x + v.y + v.z + v.w;
  ts[t] = s;
  __syncthreads();
  for (int off = 1; off < 256; off <<= 1) {
    int a = (t >= off) ? ts[t - off] : 0;
    __syncthreads();
    ts[t] += a;
    __syncthreads();
  }
  int excl = ts[t] - s;
  if (idx < M_CNT) {
    int4 o;
    o.x = excl; o.y = o.x + v.x; o.z = o.y + v.y; o.w = o.z + v.z;
    *(int4*)(offs + idx) = o;
  }
  if (t == 255) bsum[blockIdx.x] = ts[255];
}

__global__ __launch_bounds__(256) void scan2(int* __restrict__ bsum, int nb) {
  __shared__ int ts[256];
  __shared__ int carrysh;
  int t = threadIdx.x;
  int carry = 0;
  for (int base = 0; base < nb; base += 256) {
    int v = (base + t < nb) ? bsum[base + t] : 0;
    ts[t] = v;
    __syncthreads();
    for (int off = 1; off < 256; off <<= 1) {
      int a = (t >= off) ? ts[t - off] : 0;
      __syncthreads();
      ts[t] += a;
      __syncthreads();
    }
    if (base + t < nb) bsum[base + t] = carry + ts[t] - v;
    if (t == 255) carrysh = ts[255];
    __syncthreads();
    carry += carrysh;
    __syncthreads();
  }
}

// ---------------- bucket edges by dst; global slot = partial offs + bsum ----
__global__ __launch_bounds__(256) void bucket_kernel(
    const int* __restrict__ src_ap, const int* __restrict__ dst_ap,
    const int* __restrict__ src_tp, const int* __restrict__ dst_tp,
    const int* __restrict__ src_pa, const int* __restrict__ dst_pa,
    int* __restrict__ offs, const int* __restrict__ bsum, int* __restrict__ ebuf) {
  int i4 = (blockIdx.x * 256 + threadIdx.x) * 4;
  const int *sp, *dp;
  int base;
  if (i4 < E_AP) { sp = src_ap + i4; dp = dst_ap + i4; base = 0; }
  else if (i4 < E_AP + E_TP) { int j = i4 - E_AP; sp = src_tp + j; dp = dst_tp + j; base = NP; }
  else if (i4 < E_TOT) { int j = i4 - E_AP - E_TP; sp = src_pa + j; dp = dst_pa + j; base = 2 * NP; }
  else return;
  int4 s = *(const int4*)sp;
  int4 d = *(const int4*)dp;
  int gx = base + d.x, gy = base + d.y, gz = base + d.z, gw = base + d.w;
  ebuf[atomicAdd(&offs[gx], 1) + bsum[gx >> 10]] = s.x;
  ebuf[atomicAdd(&offs[gy], 1) + bsum[gy >> 10]] = s.y;
  ebuf[atomicAdd(&offs[gz], 1) + bsum[gz >> 10]] = s.z;
  ebuf[atomicAdd(&offs[gw], 1) + bsum[gw >> 10]] = s.w;
}

// ---------------- MFMA bf16 GEMM body v3 (verified 90us config) ----------------
// 128 rows/block, 2 row-tiles/wave. Weights staged once per block in LDS
// (XOR-swizzled vs 16-way bank conflict). After compute, same 32KB LDS is
// reused to stage outputs for fully coalesced 16B global stores.
template <int K, int COLS, bool HAS_OUT1>
static __device__ __forceinline__ void gemm_body(const float* __restrict__ X,
                                                 const short* __restrict__ Wt,
                                                 const float* __restrict__ bias1,
                                                 unsigned short* __restrict__ out0,
                                                 unsigned short* __restrict__ out1,
                                                 int N, int bid,
                                                 unsigned short* __restrict__ lds) {
  constexpr int NSTEP = K / 32;
  constexpr int NTILE = COLS / 16;
  constexpr int WROWB = K * 2;         // weight row bytes (256 / 128)
  constexpr int WBYTES = COLS * K * 2; // 32KB / 8KB
  const int t = threadIdx.x;
  const int lane = t & 63;
  const int w = t >> 6;
  const int m = lane & 15;
  const int quad = lane >> 4;

  // ---- A loads + bf16 convert: 2 row-tiles per wave ----
  const int r0 = bid * 128 + w * 16;   // tile0 rows r0..r0+15
  const int r1 = r0 + 64;              // tile1
  bf16x8 a0[NSTEP], a1[NSTEP];
  {
    const float* x0 = X + (size_t)min(r0 + m, N - 1) * K + quad * 8;
    const float* x1 = X + (size_t)min(r1 + m, N - 1) * K + quad * 8;
#pragma unroll
    for (int s = 0; s < NSTEP; ++s) {
      float4 v0 = *(const float4*)(x0 + s * 32);
      float4 v1 = *(const float4*)(x0 + s * 32 + 4);
      float4 u0 = *(const float4*)(x1 + s * 32);
      float4 u1 = *(const float4*)(x1 + s * 32 + 4);
      bf16x8 a;
      a[0] = f2bf(v0.x); a[1] = f2bf(v0.y); a[2] = f2bf(v0.z); a[3] = f2bf(v0.w);
      a[4] = f2bf(v1.x); a[5] = f2bf(v1.y); a[6] = f2bf(v1.z); a[7] = f2bf(v1.w);
      a0[s] = a;
      bf16x8 b;
      b[0] = f2bf(u0.x); b[1] = f2bf(u0.y); b[2] = f2bf(u0.z); b[3] = f2bf(u0.w);
      b[4] = f2bf(u1.x); b[5] = f2bf(u1.y); b[6] = f2bf(u1.z); b[7] = f2bf(u1.w);
      a1[s] = b;
    }
  }

  // ---- cooperative W -> LDS stage, swizzled dest ----
  {
    const char* wsrc = (const char*)Wt;
    char* wdst = (char*)lds;
#pragma unroll
    for (int i = 0; i < WBYTES / 4096; ++i) {
      const int byte = t * 16 + i * 4096;
      const uint4 v = *(const uint4*)(wsrc + byte);
      const int row = byte / WROWB;
      *(uint4*)(wdst + (byte ^ ((row & 7) << 4))) = v;
    }
  }
  __syncthreads();

  // ---- MFMA: per col-tile, 1 swizzled ds_read feeds 2 row-tiles ----
  f32x4 acc0[NTILE], acc1[NTILE];
#pragma unroll
  for (int ct = 0; ct < NTILE; ++ct) {
    acc0[ct] = (f32x4){0.f, 0.f, 0.f, 0.f};
    acc1[ct] = (f32x4){0.f, 0.f, 0.f, 0.f};
  }
#pragma unroll
  for (int ct = 0; ct < NTILE; ++ct) {
    const int wrow = ct * 16 + m;
    const int swx = (wrow & 7) << 4;
#pragma unroll
    for (int s = 0; s < NSTEP; ++s) {
      const int byte = wrow * WROWB + s * 64 + quad * 16;
      const bf16x8 b = *(const bf16x8*)((const char*)lds + (byte ^ swx));
      acc0[ct] = __builtin_amdgcn_mfma_f32_16x16x32_bf16(a0[s], b, acc0[ct], 0, 0, 0);
      acc1[ct] = __builtin_amdgcn_mfma_f32_16x16x32_bf16(a1[s], b, acc1[ct], 0, 0, 0);
    }
  }
  __syncthreads();  // all waves done reading W region

  // ---- stage outputs into (reused) LDS: [128 rows][COLS] bf16, swizzled ----
  constexpr int OROWB = COLS * 2;
#pragma unroll
  for (int ct = 0; ct < NTILE; ++ct) {
    const int col = ct * 16 + m;
    const float add = (HAS_OUT1 && ct >= NTILE / 2) ? bias1[col - 64] : 0.f;
#pragma unroll
    for (int rg = 0; rg < 4; ++rg) {
      const int lr0 = w * 16 + quad * 4 + rg;
      const int lr1 = lr0 + 64;
      const int b0 = lr0 * OROWB + col * 2;
      const int b1 = lr1 * OROWB + col * 2;
      *(unsigned short*)((char*)lds + (b0 ^ ((lr0 & 7) << 4))) =
          (unsigned short)f2bf(acc0[ct][rg] + add);
      *(unsigned short*)((char*)lds + (b1 ^ ((lr1 & 7) << 4))) =
          (unsigned short)f2bf(acc1[ct][rg] + add);
    }
  }
  __syncthreads();

  // ---- coalesced writeback: 16B/lane, contiguous 128B row chunks ----
  constexpr int OUTB = 128 * OROWB;    // 32KB / 16KB
#pragma unroll
  for (int i = 0; i < OUTB / 4096; ++i) {
    const int byte = t * 16 + i * 4096;
    const int row = byte / OROWB;
    const int colb = byte - row * OROWB;
    const uint4 v = *(const uint4*)((const char*)lds + (byte ^ ((row & 7) << 4)));
    const int grow = bid * 128 + row;
    if (grow < N) {
      unsigned short* dst = (HAS_OUT1 && colb >= 128) ? out1 : out0;
      *(uint4*)((char*)dst + (size_t)grow * (HD * 2) + (colb & 127)) = v;
    }
  }
}

#define GB_P ((NP + 127) / 128)
#define GB_A ((NA + 127) / 128)
#define GB_T ((NT + 127) / 128)

// single launch for all 3 layer-1 GEMMs (block-range dispatch)
__global__ __launch_bounds__(256, 4) void gemm_all(
    const float* __restrict__ x_paper, const float* __restrict__ x_author,
    const float* __restrict__ x_term,
    const short* __restrict__ Wt_np, const short* __restrict__ Wt_na,
    const short* __restrict__ Wt_tp,
    const float* __restrict__ blc, const float* __restrict__ l1_pa_bl,
    unsigned short* __restrict__ yp, unsigned short* __restrict__ P1root,
    unsigned short* __restrict__ ya, unsigned short* __restrict__ A1root,
    unsigned short* __restrict__ yt) {
  __shared__ unsigned short lds[16384];  // 32KB: W stage, then output stage
  int b = blockIdx.x;
  if (b < GB_P) {
    gemm_body<128, 128, true>(x_paper, Wt_np, blc, yp, P1root, NP, b, lds);
  } else if (b < GB_P + GB_A) {
    gemm_body<128, 128, true>(x_author, Wt_na, l1_pa_bl, ya, A1root, NA, b - GB_P, lds);
  } else {
    gemm_body<64, 64, false>(x_term, Wt_tp, nullptr, yt, nullptr, NT, b - GB_P - GB_A, lds);
  }
}

// ---------------- paper aggregation: 8 lanes/paper, 2-way edge unroll ------
__global__ __launch_bounds__(256) void paper_agg(
    const unsigned short* __restrict__ ya, const unsigned short* __restrict__ yt,
    const unsigned short* __restrict__ P1root,
    const int* __restrict__ cnt, const int* __restrict__ offs,
    const int* __restrict__ bsum,
    const int* __restrict__ ebuf, const float* __restrict__ Wfl,
    float* __restrict__ z) {
  const int wv = threadIdx.x >> 6;
  const int lane = threadIdx.x & 63;
  const int g = lane >> 3;
  const int l = lane & 7;
  const int p = blockIdx.x * 32 + wv * 8 + g;
  const bool pv = p < NP;
  const int pc = pv ? p : NP - 1;

  const int cA = cnt[pc], cT = cnt[NP + pc];
  const int startA = offs[pc] + bsum[pc >> 10] - cA;
  const int startT = offs[NP + pc] + bsum[(NP + pc) >> 10] - cT;

  const unsigned short* yab = ya + 8 * l;
  const unsigned short* ytb = yt + 8 * l;

  float accA[8], accT[8];
#pragma unroll
  for (int j = 0; j < 8; ++j) { accA[j] = 0.f; accT[j] = 0.f; }

  const int mx = max(cA, cT);
  for (int i = 0; i < mx; i += 2) {
    const bool a0 = i < cA, a1 = i + 1 < cA;
    const bool t0 = i < cT, t1 = i + 1 < cT;
    // index reads may overshoot a segment but stay inside ebuf (regions are
    // contiguous; max overshoot < max degree). Inactive slots clamp to row 0.
    int sA0 = ebuf[startA + i];
    int sA1 = ebuf[startA + i + 1];
    int sT0 = ebuf[startT + i];
    int sT1 = ebuf[startT + i + 1];
    sA0 = a0 ? sA0 : 0;
    sA1 = a1 ? sA1 : 0;
    sT0 = t0 ? sT0 : 0;
    sT1 = t1 ? sT1 : 0;
    const uint4 uA0 = *(const uint4*)(yab + (size_t)sA0 * HD);
    const uint4 uA1 = *(const uint4*)(yab + (size_t)sA1 * HD);
    const uint4 uT0 = *(const uint4*)(ytb + (size_t)sT0 * HD);
    const uint4 uT1 = *(const uint4*)(ytb + (size_t)sT1 * HD);
    acc8(accA, uA0, a0 ? 1.f : 0.f);
    acc8(accA, uA1, a1 ? 1.f : 0.f);
    acc8(accT, uT0, t0 ? 1.f : 0.f);
    acc8(accT, uT1, t1 ? 1.f : 0.f);
  }

  const float rA = 1.0f / (float)max(cA, 1);
  const float rT = 1.0f / (float)max(cT, 1);
  uint4 rt = *(const uint4*)(P1root + (size_t)pc * HD + 8 * l);
  float v[8];
  v[0] = bflo(rt.x); v[1] = bfhi(rt.x); v[2] = bflo(rt.y); v[3] = bfhi(rt.y);
  v[4] = bflo(rt.z); v[5] = bfhi(rt.z); v[6] = bflo(rt.w); v[7] = bfhi(rt.w);
  float4 pz = make_float4(0.f, 0.f, 0.f, 0.f);
#pragma unroll
  for (int j = 0; j < 8; ++j) {
    float x = v[j] + accA[j] * rA + accT[j] * rT;
    x = fmaxf(x, NEG * x);  // lrelu
    float4 wf = *(const float4*)(Wfl + (8 * l + j) * 4);
    pz.x += x * wf.x; pz.y += x * wf.y; pz.z += x * wf.z; pz.w += x * wf.w;
  }
#pragma unroll
  for (int m = 1; m < 8; m <<= 1) {
    pz.x += __shfl_xor(pz.x, m);
    pz.y += __shfl_xor(pz.y, m);
    pz.z += __shfl_xor(pz.z, m);
    pz.w += __shfl_xor(pz.w, m);
  }
  if (l == 0 && pv) *(float4*)(z + (size_t)p * NOUT) = pz;
}

// ---------------- author aggregation: 8 lanes/author, 2-way edge unroll ----
__global__ __launch_bounds__(256) void author_agg(
    const unsigned short* __restrict__ yp, const unsigned short* __restrict__ A1root,
    const float* __restrict__ z,
    const int* __restrict__ cnt, const int* __restrict__ offs,
    const int* __restrict__ bsum,
    const int* __restrict__ ebuf, const float* __restrict__ Wfr,
    const float* __restrict__ bf, float* __restrict__ out) {
  const int wv = threadIdx.x >> 6;
  const int lane = threadIdx.x & 63;
  const int g = lane >> 3;
  const int l = lane & 7;
  const int a = blockIdx.x * 32 + wv * 8 + g;
  const bool av = a < NA;
  const int ac = av ? a : NA - 1;

  const int gidx = 2 * NP + ac;
  const int c = cnt[gidx];
  const int start = offs[gidx] + bsum[gidx >> 10] - c;

  const unsigned short* ypb = yp + 8 * l;

  float acc[8];
#pragma unroll
  for (int j = 0; j < 8; ++j) acc[j] = 0.f;
  float4 az = make_float4(0.f, 0.f, 0.f, 0.f);

  for (int i = 0; i < c; i += 2) {
    const bool b1 = i + 1 < c;
    int s0 = ebuf[start + i];
    int s1 = ebuf[min(start + i + 1, E_TOT - 1)];  // pa region is last: clamp
    s1 = b1 ? s1 : 0;
    const uint4 u0 = *(const uint4*)(ypb + (size_t)s0 * HD);
    const uint4 u1 = *(const uint4*)(ypb + (size_t)s1 * HD);
    const float4 z0 = *(const float4*)(z + (size_t)s0 * NOUT);
    const float4 z1 = *(const float4*)(z + (size_t)s1 * NOUT);
    const float w1 = b1 ? 1.f : 0.f;
    acc8(acc, u0, 1.f);
    acc8(acc, u1, w1);
    az.x = fmaf(w1, z1.x, az.x + z0.x);
    az.y = fmaf(w1, z1.y, az.y + z0.y);
    az.z = fmaf(w1, z1.z, az.z + z0.z);
    az.w = fmaf(w1, z1.w, az.w + z0.w);
  }

  const float r = 1.0f / (float)max(c, 1);
  uint4 rt = *(const uint4*)(A1root + (size_t)ac * HD + 8 * l);
  float v[8];
  v[0] = bflo(rt.x); v[1] = bfhi(rt.x); v[2] = bflo(rt.y); v[3] = bfhi(rt.y);
  v[4] = bflo(rt.z); v[5] = bfhi(rt.z); v[6] = bflo(rt.w); v[7] = bfhi(rt.w);
  float4 o = make_float4(0.f, 0.f, 0.f, 0.f);
#pragma unroll
  for (int j = 0; j < 8; ++j) {
    float x = v[j] + acc[j] * r;
    x = fmaxf(x, NEG * x);
    float4 wf = *(const float4*)(Wfr + (8 * l + j) * 4);
    o.x += x * wf.x; o.y += x * wf.y; o.z += x * wf.z; o.w += x * wf.w;
  }
#pragma unroll
  for (int m = 1; m < 8; m <<= 1) {
    o.x += __shfl_xor(o.x, m);
    o.y += __shfl_xor(o.y, m);
    o.z += __shfl_xor(o.z, m);
    o.w += __shfl_xor(o.w, m);
  }
  if (l == 0 && av) {
    float4 b = *(const float4*)bf;
    o.x += az.x * r + b.x;
    o.y += az.y * r + b.y;
    o.z += az.z * r + b.z;
    o.w += az.w * r + b.w;
    *(float4*)(out + (size_t)a * NOUT) = o;
  }
}

extern "C" void kernel_launch(void* const* d_in, const int* in_sizes, int n_in,
                              void* d_out, int out_size, void* d_ws, size_t ws_size,
                              hipStream_t stream) {
  const float* x_author = (const float*)d_in[0];
  const float* x_paper  = (const float*)d_in[1];
  const float* x_term   = (const float*)d_in[2];
  const int* src_ap = (const int*)d_in[3];
  const int* dst_ap = (const int*)d_in[4];
  const int* src_pa = (const int*)d_in[5];
  const int* dst_pa = (const int*)d_in[6];
  const int* src_tp = (const int*)d_in[7];
  const int* dst_tp = (const int*)d_in[8];
  const float* l1_ap_Wl = (const float*)d_in[11];
  const float* l1_ap_bl = (const float*)d_in[12];
  const float* l1_ap_Wr = (const float*)d_in[13];
  const float* l1_pa_Wl = (const float*)d_in[17];
  const float* l1_pa_bl = (const float*)d_in[18];
  const float* l1_pa_Wr = (const float*)d_in[19];
  const float* l2_pa_Wl = (const float*)d_in[20];
  const float* l2_pa_bl = (const float*)d_in[21];
  const float* l2_pa_Wr = (const float*)d_in[22];
  const float* l1_tp_Wl = (const float*)d_in[23];
  const float* l1_tp_bl = (const float*)d_in[24];
  const float* l1_tp_Wr = (const float*)d_in[25];
  const float* lin_W = (const float*)d_in[35];
  const float* lin_b = (const float*)d_in[36];
  float* out = (float*)d_out;

  // workspace carve-up (byte-based, 16B aligned blocks)
  char* wsb = (char*)d_ws;
  auto carve = [&](size_t bytes) {
    char* p = wsb;
    wsb += (bytes + 15) & ~(size_t)15;
    return p;
  };
  unsigned short* ya = (unsigned short*)carve((size_t)NA * HD * 2);
  unsigned short* yp = (unsigned short*)carve((size_t)NP * HD * 2);
  unsigned short* yt = (unsigned short*)carve((size_t)NT * HD * 2);
  unsigned short* P1root = (unsigned short*)carve((size_t)NP * HD * 2);
  unsigned short* A1root = (unsigned short*)carve((size_t)NA * HD * 2);
  float* z = (float*)carve((size_t)NP * NOUT * 4);
  int* cnt = (int*)carve((size_t)M_CNT * 4);
  int* offs = (int*)carve((size_t)M_CNT * 4);
  int* bsum = (int*)carve((size_t)SCAN_NB * 4);
  int* ebuf = (int*)carve((size_t)E_TOT * 4);
  short* Wt_np = (short*)carve(128 * 128 * 2);
  short* Wt_na = (short*)carve(128 * 128 * 2);
  short* Wt_tp = (short*)carve(64 * 64 * 2);
  float* blc = (float*)carve(HD * 4);
  float* Wfl = (float*)carve(HD * NOUT * 4);
  float* Wfr = (float*)carve(HD * NOUT * 4);
  float* bf  = (float*)carve(NOUT * 4);

  // weight prep + cnt zeroing in one launch (memset folded in)
  build_zero_kernel<<<BZ_NB, 256, 0, stream>>>(
      l1_ap_Wl, l1_ap_bl, l1_ap_Wr, l1_pa_Wl, l1_pa_bl, l1_pa_Wr,
      l1_tp_Wl, l1_tp_bl, l1_tp_Wr, l2_pa_Wl, l2_pa_bl, l2_pa_Wr,
      lin_W, lin_b, Wt_np, Wt_na, Wt_tp, blc, Wfl, Wfr, bf, cnt);
  count_all<<<(E_TOT / 4 + 255) / 256, 256, 0, stream>>>(dst_ap, dst_tp, dst_pa, cnt);

  // exclusive scan of cnt -> offs (partial) + bsum (scanned block offsets)
  scan1<<<SCAN_NB, 256, 0, stream>>>(cnt, offs, bsum);
  scan2<<<1, 256, 0, stream>>>(bsum, SCAN_NB);

  // all three layer-1 GEMMs in one launch (verified v3 structure)
  gemm_all<<<GB_P + GB_A + GB_T, 256, 0, stream>>>(
      x_paper, x_author, x_term, Wt_np, Wt_na, Wt_tp, blc, l1_pa_bl,
      yp, P1root, ya, A1root, yt);

  // CSR bucket: slot = partial offs (atomic bump) + scanned block offset
  bucket_kernel<<<(E_TOT / 4 + 255) / 256, 256, 0, stream>>>(src_ap, dst_ap, src_tp, dst_tp,
                                                             src_pa, dst_pa, offs, bsum, ebuf);

  // gather-based aggregation: 8 lanes/node, 8 nodes/wave, 2-way edge unroll
  paper_agg<<<(NP + 31) / 32, 256, 0, stream>>>(ya, yt, P1root, cnt, offs, bsum, ebuf, Wfl, z);
  author_agg<<<(NA + 31) / 32, 256, 0, stream>>>(yp, A1root, z, cnt, offs, bsum, ebuf, Wfr, bf, out);
}

// Round 8
// 454.510 us; speedup vs baseline: 1.1438x; 1.0328x over previous
//
#include <hip/hip_runtime.h>

#define NA 100000
#define NP 200000
#define NT 50000
#define E_AP 400000
#define E_PA 400000
#define E_TP 300000
#define E_TOT (E_AP + E_TP + E_PA)
#define HD 64
#define NOUT 4
#define NEG 0.01f
#define M_CNT (2 * NP + NA)          /* 500000 concatenated count slots */
#define SCAN_NB ((M_CNT + 1023) / 1024)

typedef __attribute__((ext_vector_type(8))) short bf16x8;
typedef __attribute__((ext_vector_type(4))) float f32x4;

static __device__ __forceinline__ short f2bf(float f) {
  unsigned u = __float_as_uint(f);
  unsigned r = (u + 0x7FFFu + ((u >> 16) & 1u)) >> 16;  // RNE
  return (short)r;
}
static __device__ __forceinline__ float bflo(unsigned u) {
  return __uint_as_float(u << 16);
}
static __device__ __forceinline__ float bfhi(unsigned u) {
  return __uint_as_float(u & 0xFFFF0000u);
}

// weighted bf16x8 accumulate; w==1.0 is exact add, w==0.0 is exact no-op.
static __device__ __forceinline__ void acc8(float* acc, uint4 u, float w) {
  acc[0] = fmaf(w, bflo(u.x), acc[0]);
  acc[1] = fmaf(w, bfhi(u.x), acc[1]);
  acc[2] = fmaf(w, bflo(u.y), acc[2]);
  acc[3] = fmaf(w, bfhi(u.y), acc[3]);
  acc[4] = fmaf(w, bflo(u.z), acc[4]);
  acc[5] = fmaf(w, bfhi(u.z), acc[5]);
  acc[6] = fmaf(w, bflo(u.w), acc[6]);
  acc[7] = fmaf(w, bfhi(u.w), acc[7]);
}

// ---------------- weight prep (parallel) + cnt zeroing fused ----------------
#define R_NP 16384
#define R_NA 32768
#define R_TP 36864
#define R_BLC 36928
#define R_WFL 37184
#define R_WFR 37440
#define R_BF 37444
#define BZ_NB ((M_CNT / 4 + 255) / 256)   /* 489 blocks covers zeroing + build */
__global__ __launch_bounds__(256) void build_zero_kernel(
    const float* __restrict__ l1_ap_Wl, const float* __restrict__ l1_ap_bl,
    const float* __restrict__ l1_ap_Wr,
    const float* __restrict__ l1_pa_Wl, const float* __restrict__ l1_pa_bl,
    const float* __restrict__ l1_pa_Wr,
    const float* __restrict__ l1_tp_Wl, const float* __restrict__ l1_tp_bl,
    const float* __restrict__ l1_tp_Wr,
    const float* __restrict__ l2_Wl, const float* __restrict__ l2_bl,
    const float* __restrict__ l2_Wr,
    const float* __restrict__ lin_W, const float* __restrict__ lin_b,
    short* __restrict__ Wt_np, short* __restrict__ Wt_na, short* __restrict__ Wt_tp,
    float* __restrict__ blc, float* __restrict__ Wfl, float* __restrict__ Wfr,
    float* __restrict__ bf, int* __restrict__ cnt) {
  int t = blockIdx.x * 256 + threadIdx.x;
  // zero the degree counters (replaces hipMemsetAsync)
  int z4 = t * 4;
  if (z4 < M_CNT) *(int4*)(cnt + z4) = make_int4(0, 0, 0, 0);

  if (t < R_NP) {
    int c = t >> 7, k = t & 127;
    float v = (c < 64) ? l1_pa_Wl[k * 64 + c]
                       : (l1_ap_Wr[k * 64 + (c - 64)] + l1_tp_Wr[k * 64 + (c - 64)]);
    Wt_np[t] = f2bf(v);
  } else if (t < R_NA) {
    int i = t - R_NP;
    int c = i >> 7, k = i & 127;
    float v = (c < 64) ? l1_ap_Wl[k * 64 + c] : l1_pa_Wr[k * 64 + (c - 64)];
    Wt_na[i] = f2bf(v);
  } else if (t < R_TP) {
    int i = t - R_NA;
    int c = i >> 6, k = i & 63;
    Wt_tp[i] = f2bf(l1_tp_Wl[k * 64 + c]);
  } else if (t < R_BLC) {
    int c = t - R_TP;
    blc[c] = l1_ap_bl[c] + l1_tp_bl[c];
  } else if (t < R_WFL) {
    int i = t - R_BLC;
    int k = i >> 2, c = i & 3;
    float s = 0.f;
    for (int j = 0; j < HD; ++j) s += l2_Wl[k * HD + j] * lin_W[j * NOUT + c];
    Wfl[i] = s;
  } else if (t < R_WFR) {
    int i = t - R_WFL;
    int k = i >> 2, c = i & 3;
    float s = 0.f;
    for (int j = 0; j < HD; ++j) s += l2_Wr[k * HD + j] * lin_W[j * NOUT + c];
    Wfr[i] = s;
  } else if (t < R_BF) {
    int c = t - R_WFR;
    float s = lin_b[c];
    for (int j = 0; j < HD; ++j) s += l2_bl[j] * lin_W[j * NOUT + c];
    bf[c] = s;
  }
}

// ---------------- exclusive scan (2 kernels; block-offset add folded into
// bucket/agg consumers via bsum lookup) ----------------
__global__ __launch_bounds__(256) void scan1(const int* __restrict__ cnt,
                                             int* __restrict__ offs,
                                             int* __restrict__ bsum) {
  __shared__ int ts[256];
  int t = threadIdx.x;
  int idx = blockIdx.x * 1024 + t * 4;
  int4 v = make_int4(0, 0, 0, 0);
  if (idx < M_CNT) v = *(const int4*)(cnt + idx);
  int s = v.x + v.y + v.z + v.w;
  ts[t] = s;
  __syncthreads();
  for (int off = 1; off < 256; off <<= 1) {
    int a = (t >= off) ? ts[t - off] : 0;
    __syncthreads();
    ts[t] += a;
    __syncthreads();
  }
  int excl = ts[t] - s;
  if (idx < M_CNT) {
    int4 o;
    o.x = excl; o.y = o.x + v.x; o.z = o.y + v.y; o.w = o.z + v.z;
    *(int4*)(offs + idx) = o;
  }
  if (t == 255) bsum[blockIdx.x] = ts[255];
}

__global__ __launch_bounds__(256) void scan2(int* __restrict__ bsum, int nb) {
  __shared__ int ts[256];
  __shared__ int carrysh;
  int t = threadIdx.x;
  int carry = 0;
  for (int base = 0; base < nb; base += 256) {
    int v = (base + t < nb) ? bsum[base + t] : 0;
    ts[t] = v;
    __syncthreads();
    for (int off = 1; off < 256; off <<= 1) {
      int a = (t >= off) ? ts[t - off] : 0;
      __syncthreads();
      ts[t] += a;
      __syncthreads();
    }
    if (base + t < nb) bsum[base + t] = carry + ts[t] - v;
    if (t == 255) carrysh = ts[255];
    __syncthreads();
    carry += carrysh;
    __syncthreads();
  }
}

// ---------------- MFMA bf16 GEMM body v3 (verified 82us config) ----------------
// 128 rows/block, 2 row-tiles/wave. Weights staged once per block in LDS
// (XOR-swizzled vs 16-way bank conflict). After compute, same 32KB LDS is
// reused to stage outputs for fully coalesced 16B global stores.
template <int K, int COLS, bool HAS_OUT1>
static __device__ __forceinline__ void gemm_body(const float* __restrict__ X,
                                                 const short* __restrict__ Wt,
                                                 const float* __restrict__ bias1,
                                                 unsigned short* __restrict__ out0,
                                                 unsigned short* __restrict__ out1,
                                                 int N, int bid,
                                                 unsigned short* __restrict__ lds) {
  constexpr int NSTEP = K / 32;
  constexpr int NTILE = COLS / 16;
  constexpr int WROWB = K * 2;         // weight row bytes (256 / 128)
  constexpr int WBYTES = COLS * K * 2; // 32KB / 8KB
  const int t = threadIdx.x;
  const int lane = t & 63;
  const int w = t >> 6;
  const int m = lane & 15;
  const int quad = lane >> 4;

  // ---- A loads + bf16 convert: 2 row-tiles per wave ----
  const int r0 = bid * 128 + w * 16;   // tile0 rows r0..r0+15
  const int r1 = r0 + 64;              // tile1
  bf16x8 a0[NSTEP], a1[NSTEP];
  {
    const float* x0 = X + (size_t)min(r0 + m, N - 1) * K + quad * 8;
    const float* x1 = X + (size_t)min(r1 + m, N - 1) * K + quad * 8;
#pragma unroll
    for (int s = 0; s < NSTEP; ++s) {
      float4 v0 = *(const float4*)(x0 + s * 32);
      float4 v1 = *(const float4*)(x0 + s * 32 + 4);
      float4 u0 = *(const float4*)(x1 + s * 32);
      float4 u1 = *(const float4*)(x1 + s * 32 + 4);
      bf16x8 a;
      a[0] = f2bf(v0.x); a[1] = f2bf(v0.y); a[2] = f2bf(v0.z); a[3] = f2bf(v0.w);
      a[4] = f2bf(v1.x); a[5] = f2bf(v1.y); a[6] = f2bf(v1.z); a[7] = f2bf(v1.w);
      a0[s] = a;
      bf16x8 b;
      b[0] = f2bf(u0.x); b[1] = f2bf(u0.y); b[2] = f2bf(u0.z); b[3] = f2bf(u0.w);
      b[4] = f2bf(u1.x); b[5] = f2bf(u1.y); b[6] = f2bf(u1.z); b[7] = f2bf(u1.w);
      a1[s] = b;
    }
  }

  // ---- cooperative W -> LDS stage, swizzled dest ----
  {
    const char* wsrc = (const char*)Wt;
    char* wdst = (char*)lds;
#pragma unroll
    for (int i = 0; i < WBYTES / 4096; ++i) {
      const int byte = t * 16 + i * 4096;
      const uint4 v = *(const uint4*)(wsrc + byte);
      const int row = byte / WROWB;
      *(uint4*)(wdst + (byte ^ ((row & 7) << 4))) = v;
    }
  }
  __syncthreads();

  // ---- MFMA: per col-tile, 1 swizzled ds_read feeds 2 row-tiles ----
  f32x4 acc0[NTILE], acc1[NTILE];
#pragma unroll
  for (int ct = 0; ct < NTILE; ++ct) {
    acc0[ct] = (f32x4){0.f, 0.f, 0.f, 0.f};
    acc1[ct] = (f32x4){0.f, 0.f, 0.f, 0.f};
  }
#pragma unroll
  for (int ct = 0; ct < NTILE; ++ct) {
    const int wrow = ct * 16 + m;
    const int swx = (wrow & 7) << 4;
#pragma unroll
    for (int s = 0; s < NSTEP; ++s) {
      const int byte = wrow * WROWB + s * 64 + quad * 16;
      const bf16x8 b = *(const bf16x8*)((const char*)lds + (byte ^ swx));
      acc0[ct] = __builtin_amdgcn_mfma_f32_16x16x32_bf16(a0[s], b, acc0[ct], 0, 0, 0);
      acc1[ct] = __builtin_amdgcn_mfma_f32_16x16x32_bf16(a1[s], b, acc1[ct], 0, 0, 0);
    }
  }
  __syncthreads();  // all waves done reading W region

  // ---- stage outputs into (reused) LDS: [128 rows][COLS] bf16, swizzled ----
  constexpr int OROWB = COLS * 2;
#pragma unroll
  for (int ct = 0; ct < NTILE; ++ct) {
    const int col = ct * 16 + m;
    const float add = (HAS_OUT1 && ct >= NTILE / 2) ? bias1[col - 64] : 0.f;
#pragma unroll
    for (int rg = 0; rg < 4; ++rg) {
      const int lr0 = w * 16 + quad * 4 + rg;
      const int lr1 = lr0 + 64;
      const int b0 = lr0 * OROWB + col * 2;
      const int b1 = lr1 * OROWB + col * 2;
      *(unsigned short*)((char*)lds + (b0 ^ ((lr0 & 7) << 4))) =
          (unsigned short)f2bf(acc0[ct][rg] + add);
      *(unsigned short*)((char*)lds + (b1 ^ ((lr1 & 7) << 4))) =
          (unsigned short)f2bf(acc1[ct][rg] + add);
    }
  }
  __syncthreads();

  // ---- coalesced writeback: 16B/lane, contiguous 128B row chunks ----
  constexpr int OUTB = 128 * OROWB;    // 32KB / 16KB
#pragma unroll
  for (int i = 0; i < OUTB / 4096; ++i) {
    const int byte = t * 16 + i * 4096;
    const int row = byte / OROWB;
    const int colb = byte - row * OROWB;
    const uint4 v = *(const uint4*)((const char*)lds + (byte ^ ((row & 7) << 4)));
    const int grow = bid * 128 + row;
    if (grow < N) {
      unsigned short* dst = (HAS_OUT1 && colb >= 128) ? out1 : out0;
      *(uint4*)((char*)dst + (size_t)grow * (HD * 2) + (colb & 127)) = v;
    }
  }
}

#define GB_P ((NP + 127) / 128)
#define GB_A ((NA + 127) / 128)
#define GB_T ((NT + 127) / 128)
#define CNT_NB ((E_TOT / 4 + 255) / 256)   /* 1075 edge-chunk blocks */

// ---------------- combo1: degree count (blocks [0,CNT_NB)) runs concurrently
// with author+term GEMMs (independent phases share one dispatch) ----------
__global__ __launch_bounds__(256, 4) void count_gemm_ta(
    const int* __restrict__ dst_ap, const int* __restrict__ dst_tp,
    const int* __restrict__ dst_pa, int* __restrict__ cnt,
    const float* __restrict__ x_author, const float* __restrict__ x_term,
    const short* __restrict__ Wt_na, const short* __restrict__ Wt_tp,
    const float* __restrict__ l1_pa_bl,
    unsigned short* __restrict__ ya, unsigned short* __restrict__ A1root,
    unsigned short* __restrict__ yt) {
  __shared__ unsigned short lds[16384];
  int b = blockIdx.x;
  if (b < CNT_NB) {
    int i4 = (b * 256 + threadIdx.x) * 4;
    const int* p;
    int base;
    if (i4 < E_AP) { p = dst_ap + i4; base = 0; }
    else if (i4 < E_AP + E_TP) { p = dst_tp + (i4 - E_AP); base = NP; }
    else if (i4 < E_TOT) { p = dst_pa + (i4 - E_AP - E_TP); base = 2 * NP; }
    else return;
    int4 d = *(const int4*)p;
    atomicAdd(&cnt[base + d.x], 1);
    atomicAdd(&cnt[base + d.y], 1);
    atomicAdd(&cnt[base + d.z], 1);
    atomicAdd(&cnt[base + d.w], 1);
  } else if (b < CNT_NB + GB_A) {
    gemm_body<128, 128, true>(x_author, Wt_na, l1_pa_bl, ya, A1root, NA, b - CNT_NB, lds);
  } else {
    gemm_body<64, 64, false>(x_term, Wt_tp, nullptr, yt, nullptr, NT,
                             b - CNT_NB - GB_A, lds);
  }
}

// ---------------- combo2: CSR bucket (blocks [0,CNT_NB)) runs concurrently
// with the paper GEMM ----------------
__global__ __launch_bounds__(256, 4) void bucket_gemm_p(
    const int* __restrict__ src_ap, const int* __restrict__ dst_ap,
    const int* __restrict__ src_tp, const int* __restrict__ dst_tp,
    const int* __restrict__ src_pa, const int* __restrict__ dst_pa,
    int* __restrict__ offs, const int* __restrict__ bsum, int* __restrict__ ebuf,
    const float* __restrict__ x_paper, const short* __restrict__ Wt_np,
    const float* __restrict__ blc,
    unsigned short* __restrict__ yp, unsigned short* __restrict__ P1root) {
  __shared__ unsigned short lds[16384];
  int b = blockIdx.x;
  if (b < CNT_NB) {
    int i4 = (b * 256 + threadIdx.x) * 4;
    const int *sp, *dp;
    int base;
    if (i4 < E_AP) { sp = src_ap + i4; dp = dst_ap + i4; base = 0; }
    else if (i4 < E_AP + E_TP) { int j = i4 - E_AP; sp = src_tp + j; dp = dst_tp + j; base = NP; }
    else if (i4 < E_TOT) { int j = i4 - E_AP - E_TP; sp = src_pa + j; dp = dst_pa + j; base = 2 * NP; }
    else return;
    int4 s = *(const int4*)sp;
    int4 d = *(const int4*)dp;
    int gx = base + d.x, gy = base + d.y, gz = base + d.z, gw = base + d.w;
    ebuf[atomicAdd(&offs[gx], 1) + bsum[gx >> 10]] = s.x;
    ebuf[atomicAdd(&offs[gy], 1) + bsum[gy >> 10]] = s.y;
    ebuf[atomicAdd(&offs[gz], 1) + bsum[gz >> 10]] = s.z;
    ebuf[atomicAdd(&offs[gw], 1) + bsum[gw >> 10]] = s.w;
  } else {
    gemm_body<128, 128, true>(x_paper, Wt_np, blc, yp, P1root, NP, b - CNT_NB, lds);
  }
}

// ---------------- paper aggregation: 8 lanes/paper, 2-way edge unroll ------
__global__ __launch_bounds__(256) void paper_agg(
    const unsigned short* __restrict__ ya, const unsigned short* __restrict__ yt,
    const unsigned short* __restrict__ P1root,
    const int* __restrict__ cnt, const int* __restrict__ offs,
    const int* __restrict__ bsum,
    const int* __restrict__ ebuf, const float* __restrict__ Wfl,
    float* __restrict__ z) {
  const int wv = threadIdx.x >> 6;
  const int lane = threadIdx.x & 63;
  const int g = lane >> 3;
  const int l = lane & 7;
  const int p = blockIdx.x * 32 + wv * 8 + g;
  const bool pv = p < NP;
  const int pc = pv ? p : NP - 1;

  const int cA = cnt[pc], cT = cnt[NP + pc];
  const int startA = offs[pc] + bsum[pc >> 10] - cA;
  const int startT = offs[NP + pc] + bsum[(NP + pc) >> 10] - cT;

  const unsigned short* yab = ya + 8 * l;
  const unsigned short* ytb = yt + 8 * l;

  float accA[8], accT[8];
#pragma unroll
  for (int j = 0; j < 8; ++j) { accA[j] = 0.f; accT[j] = 0.f; }

  const int mx = max(cA, cT);
  for (int i = 0; i < mx; i += 2) {
    const bool a0 = i < cA, a1 = i + 1 < cA;
    const bool t0 = i < cT, t1 = i + 1 < cT;
    // index reads may overshoot a segment but stay inside ebuf (regions are
    // contiguous; max overshoot < max degree). Inactive slots clamp to row 0.
    int sA0 = ebuf[startA + i];
    int sA1 = ebuf[startA + i + 1];
    int sT0 = ebuf[startT + i];
    int sT1 = ebuf[startT + i + 1];
    sA0 = a0 ? sA0 : 0;
    sA1 = a1 ? sA1 : 0;
    sT0 = t0 ? sT0 : 0;
    sT1 = t1 ? sT1 : 0;
    const uint4 uA0 = *(const uint4*)(yab + (size_t)sA0 * HD);
    const uint4 uA1 = *(const uint4*)(yab + (size_t)sA1 * HD);
    const uint4 uT0 = *(const uint4*)(ytb + (size_t)sT0 * HD);
    const uint4 uT1 = *(const uint4*)(ytb + (size_t)sT1 * HD);
    acc8(accA, uA0, a0 ? 1.f : 0.f);
    acc8(accA, uA1, a1 ? 1.f : 0.f);
    acc8(accT, uT0, t0 ? 1.f : 0.f);
    acc8(accT, uT1, t1 ? 1.f : 0.f);
  }

  const float rA = 1.0f / (float)max(cA, 1);
  const float rT = 1.0f / (float)max(cT, 1);
  uint4 rt = *(const uint4*)(P1root + (size_t)pc * HD + 8 * l);
  float v[8];
  v[0] = bflo(rt.x); v[1] = bfhi(rt.x); v[2] = bflo(rt.y); v[3] = bfhi(rt.y);
  v[4] = bflo(rt.z); v[5] = bfhi(rt.z); v[6] = bflo(rt.w); v[7] = bfhi(rt.w);
  float4 pz = make_float4(0.f, 0.f, 0.f, 0.f);
#pragma unroll
  for (int j = 0; j < 8; ++j) {
    float x = v[j] + accA[j] * rA + accT[j] * rT;
    x = fmaxf(x, NEG * x);  // lrelu
    float4 wf = *(const float4*)(Wfl + (8 * l + j) * 4);
    pz.x += x * wf.x; pz.y += x * wf.y; pz.z += x * wf.z; pz.w += x * wf.w;
  }
#pragma unroll
  for (int m = 1; m < 8; m <<= 1) {
    pz.x += __shfl_xor(pz.x, m);
    pz.y += __shfl_xor(pz.y, m);
    pz.z += __shfl_xor(pz.z, m);
    pz.w += __shfl_xor(pz.w, m);
  }
  if (l == 0 && pv) *(float4*)(z + (size_t)p * NOUT) = pz;
}

// ---------------- author aggregation: 8 lanes/author, 2-way edge unroll ----
__global__ __launch_bounds__(256) void author_agg(
    const unsigned short* __restrict__ yp, const unsigned short* __restrict__ A1root,
    const float* __restrict__ z,
    const int* __restrict__ cnt, const int* __restrict__ offs,
    const int* __restrict__ bsum,
    const int* __restrict__ ebuf, const float* __restrict__ Wfr,
    const float* __restrict__ bf, float* __restrict__ out) {
  const int wv = threadIdx.x >> 6;
  const int lane = threadIdx.x & 63;
  const int g = lane >> 3;
  const int l = lane & 7;
  const int a = blockIdx.x * 32 + wv * 8 + g;
  const bool av = a < NA;
  const int ac = av ? a : NA - 1;

  const int gidx = 2 * NP + ac;
  const int c = cnt[gidx];
  const int start = offs[gidx] + bsum[gidx >> 10] - c;

  const unsigned short* ypb = yp + 8 * l;

  float acc[8];
#pragma unroll
  for (int j = 0; j < 8; ++j) acc[j] = 0.f;
  float4 az = make_float4(0.f, 0.f, 0.f, 0.f);

  for (int i = 0; i < c; i += 2) {
    const bool b1 = i + 1 < c;
    int s0 = ebuf[start + i];
    int s1 = ebuf[min(start + i + 1, E_TOT - 1)];  // pa region is last: clamp
    s1 = b1 ? s1 : 0;
    const uint4 u0 = *(const uint4*)(ypb + (size_t)s0 * HD);
    const uint4 u1 = *(const uint4*)(ypb + (size_t)s1 * HD);
    const float4 z0 = *(const float4*)(z + (size_t)s0 * NOUT);
    const float4 z1 = *(const float4*)(z + (size_t)s1 * NOUT);
    const float w1 = b1 ? 1.f : 0.f;
    acc8(acc, u0, 1.f);
    acc8(acc, u1, w1);
    az.x = fmaf(w1, z1.x, az.x + z0.x);
    az.y = fmaf(w1, z1.y, az.y + z0.y);
    az.z = fmaf(w1, z1.z, az.z + z0.z);
    az.w = fmaf(w1, z1.w, az.w + z0.w);
  }

  const float r = 1.0f / (float)max(c, 1);
  uint4 rt = *(const uint4*)(A1root + (size_t)ac * HD + 8 * l);
  float v[8];
  v[0] = bflo(rt.x); v[1] = bfhi(rt.x); v[2] = bflo(rt.y); v[3] = bfhi(rt.y);
  v[4] = bflo(rt.z); v[5] = bfhi(rt.z); v[6] = bflo(rt.w); v[7] = bfhi(rt.w);
  float4 o = make_float4(0.f, 0.f, 0.f, 0.f);
#pragma unroll
  for (int j = 0; j < 8; ++j) {
    float x = v[j] + acc[j] * r;
    x = fmaxf(x, NEG * x);
    float4 wf = *(const float4*)(Wfr + (8 * l + j) * 4);
    o.x += x * wf.x; o.y += x * wf.y; o.z += x * wf.z; o.w += x * wf.w;
  }
#pragma unroll
  for (int m = 1; m < 8; m <<= 1) {
    o.x += __shfl_xor(o.x, m);
    o.y += __shfl_xor(o.y, m);
    o.z += __shfl_xor(o.z, m);
    o.w += __shfl_xor(o.w, m);
  }
  if (l == 0 && av) {
    float4 b = *(const float4*)bf;
    o.x += az.x * r + b.x;
    o.y += az.y * r + b.y;
    o.z += az.z * r + b.z;
    o.w += az.w * r + b.w;
    *(float4*)(out + (size_t)a * NOUT) = o;
  }
}

extern "C" void kernel_launch(void* const* d_in, const int* in_sizes, int n_in,
                              void* d_out, int out_size, void* d_ws, size_t ws_size,
                              hipStream_t stream) {
  const float* x_author = (const float*)d_in[0];
  const float* x_paper  = (const float*)d_in[1];
  const float* x_term   = (const float*)d_in[2];
  const int* src_ap = (const int*)d_in[3];
  const int* dst_ap = (const int*)d_in[4];
  const int* src_pa = (const int*)d_in[5];
  const int* dst_pa = (const int*)d_in[6];
  const int* src_tp = (const int*)d_in[7];
  const int* dst_tp = (const int*)d_in[8];
  const float* l1_ap_Wl = (const float*)d_in[11];
  const float* l1_ap_bl = (const float*)d_in[12];
  const float* l1_ap_Wr = (const float*)d_in[13];
  const float* l1_pa_Wl = (const float*)d_in[17];
  const float* l1_pa_bl = (const float*)d_in[18];
  const float* l1_pa_Wr = (const float*)d_in[19];
  const float* l2_pa_Wl = (const float*)d_in[20];
  const float* l2_pa_bl = (const float*)d_in[21];
  const float* l2_pa_Wr = (const float*)d_in[22];
  const float* l1_tp_Wl = (const float*)d_in[23];
  const float* l1_tp_bl = (const float*)d_in[24];
  const float* l1_tp_Wr = (const float*)d_in[25];
  const float* lin_W = (const float*)d_in[35];
  const float* lin_b = (const float*)d_in[36];
  float* out = (float*)d_out;

  // workspace carve-up (byte-based, 16B aligned blocks)
  char* wsb = (char*)d_ws;
  auto carve = [&](size_t bytes) {
    char* p = wsb;
    wsb += (bytes + 15) & ~(size_t)15;
    return p;
  };
  unsigned short* ya = (unsigned short*)carve((size_t)NA * HD * 2);
  unsigned short* yp = (unsigned short*)carve((size_t)NP * HD * 2);
  unsigned short* yt = (unsigned short*)carve((size_t)NT * HD * 2);
  unsigned short* P1root = (unsigned short*)carve((size_t)NP * HD * 2);
  unsigned short* A1root = (unsigned short*)carve((size_t)NA * HD * 2);
  float* z = (float*)carve((size_t)NP * NOUT * 4);
  int* cnt = (int*)carve((size_t)M_CNT * 4);
  int* offs = (int*)carve((size_t)M_CNT * 4);
  int* bsum = (int*)carve((size_t)SCAN_NB * 4);
  int* ebuf = (int*)carve((size_t)E_TOT * 4);
  short* Wt_np = (short*)carve(128 * 128 * 2);
  short* Wt_na = (short*)carve(128 * 128 * 2);
  short* Wt_tp = (short*)carve(64 * 64 * 2);
  float* blc = (float*)carve(HD * 4);
  float* Wfl = (float*)carve(HD * NOUT * 4);
  float* Wfr = (float*)carve(HD * NOUT * 4);
  float* bf  = (float*)carve(NOUT * 4);

  // weight prep + cnt zeroing in one launch (memset folded in)
  build_zero_kernel<<<BZ_NB, 256, 0, stream>>>(
      l1_ap_Wl, l1_ap_bl, l1_ap_Wr, l1_pa_Wl, l1_pa_bl, l1_pa_Wr,
      l1_tp_Wl, l1_tp_bl, l1_tp_Wr, l2_pa_Wl, l2_pa_bl, l2_pa_Wr,
      lin_W, lin_b, Wt_np, Wt_na, Wt_tp, blc, Wfl, Wfr, bf, cnt);

  // combo1: degree count || author+term GEMMs (independent)
  count_gemm_ta<<<CNT_NB + GB_A + GB_T, 256, 0, stream>>>(
      dst_ap, dst_tp, dst_pa, cnt, x_author, x_term, Wt_na, Wt_tp, l1_pa_bl,
      ya, A1root, yt);

  // exclusive scan of cnt -> offs (partial) + bsum (scanned block offsets)
  scan1<<<SCAN_NB, 256, 0, stream>>>(cnt, offs, bsum);
  scan2<<<1, 256, 0, stream>>>(bsum, SCAN_NB);

  // combo2: CSR bucket || paper GEMM (independent)
  bucket_gemm_p<<<CNT_NB + GB_P, 256, 0, stream>>>(
      src_ap, dst_ap, src_tp, dst_tp, src_pa, dst_pa, offs, bsum, ebuf,
      x_paper, Wt_np, blc, yp, P1root);

  // gather-based aggregation: 8 lanes/node, 8 nodes/wave, 2-way edge unroll
  paper_agg<<<(NP + 31) / 32, 256, 0, stream>>>(ya, yt, P1root, cnt, offs, bsum, ebuf, Wfl, z);
  author_agg<<<(NA + 31) / 32, 256, 0, stream>>>(yp, A1root, z, cnt, offs, bsum, ebuf, Wfr, bf, out);
}